// Round 1
// baseline (125.856 us; speedup 1.0000x reference)
//
#include <hip/hip_runtime.h>

typedef _Float16 h4 __attribute__((ext_vector_type(4)));
typedef float f4 __attribute__((ext_vector_type(4)));

#define NPTS 4096
#define WS_SXY 0
#define WS_W2H (32*1024)
#define WS_HWS (64*1024)

// ---------------- prep: pack s.xy (float2) and w2 -> fragment-ordered fp16 ----------------
__global__ __launch_bounds__(256) void prep_kernel(const float* __restrict__ s,
                                                   const float* __restrict__ w2,
                                                   float2* __restrict__ sxy,
                                                   h4* __restrict__ w2h) {
  int idx = blockIdx.x * 256 + threadIdx.x;
  if (idx < NPTS) {
    float2 p; p.x = s[idx*4]; p.y = s[idx*4+1];
    sxy[idx] = p;
  }
  int fi = idx - NPTS;
  if (fi >= 0 && fi < 2048) {
    // B fragment for v_mfma_f32_16x16x16f16: lane l holds B[k][col], col=l&15, k=4*(l>>4)+i
    int l = fi & 63, ks = (fi >> 6) & 3, nt = fi >> 8;
    int o = 16*nt + (l & 15);          // output channel (col of B = row of w2)
    int cb = 16*ks + 4*(l >> 4);       // input channel (k dim)
    const float* wr = w2 + o*64 + cb;
    h4 v;
    v[0] = (_Float16)wr[0]; v[1] = (_Float16)wr[1];
    v[2] = (_Float16)wr[2]; v[3] = (_Float16)wr[3];
    w2h[fi] = v;
  }
}

// ---------------- kernel 1: per-row distances, exact top-32, edge MLP, masked max ----------------
__global__ __launch_bounds__(256) void neigh_kernel(
    const float* __restrict__ s, const float* __restrict__ w1,
    const float* __restrict__ b1, const float* __restrict__ b2,
    const float2* __restrict__ sxy, const h4* __restrict__ w2h,
    float* __restrict__ hws) {
  const int i = blockIdx.x;
  const int t = threadIdx.x;

  __shared__ unsigned hist[256];
  __shared__ unsigned wsum[4];
  __shared__ int ctr[4];          // 0: chosen bucket, 1: below, 2: nsel, 3: neq
  __shared__ int selidx[32];
  __shared__ int eqlist[256];
  __shared__ float w1s[320];
  __shared__ float b1s[64];
  __shared__ float b2s[128];
  __shared__ float xk[32][9];     // padded to 9 to spread banks
  __shared__ float maskv[32];

  for (int idx = t; idx < 320; idx += 256) w1s[idx] = w1[idx];
  if (t < 64)  b1s[t] = b1[t];
  if (t < 128) b2s[t] = b2[t];

  const float4 si = ((const float4*)s)[i];

  // ---- distances (keys stay in registers; bitwise-IEEE to match np ref) ----
  unsigned key[16];
#pragma unroll
  for (int it = 0; it < 16; ++it) {
    int j = t + (it << 8);
    float2 p = sxy[j];
    float dx = __fsub_rn(si.x, p.x);
    float dy = __fsub_rn(si.y, p.y);
    float a = __fadd_rn(__fmul_rn(dx, dx), 1e-6f);
    float b = __fadd_rn(__fmul_rn(dy, dy), 1e-6f);
    key[it] = __float_as_uint(__fsqrt_rn(__fadd_rn(a, b)));  // positive -> uint order == float order
  }

  // ---- exact radix select: find key of rank-32 smallest ----
  unsigned prefix = 0;
  int want = 32;
#pragma unroll
  for (int r = 0; r < 4; ++r) {
    const int shift = 24 - 8*r;
    __syncthreads();
    hist[t] = 0;
    __syncthreads();
    unsigned himask = (r == 0) ? 0u : (0xFFFFFFFFu << ((shift + 8) & 31));
#pragma unroll
    for (int it = 0; it < 16; ++it) {
      unsigned k = key[it];
      if ((k & himask) == prefix)
        atomicAdd(&hist[(k >> shift) & 255], 1u);
    }
    __syncthreads();
    unsigned hv = hist[t];
    unsigned v = hv;
    int lane = t & 63;
#pragma unroll
    for (int off = 1; off < 64; off <<= 1) {
      unsigned n = __shfl_up(v, off, 64);
      if (lane >= off) v += n;
    }
    if (lane == 63) wsum[t >> 6] = v;
    __syncthreads();
    unsigned add = 0;
    for (int ww = 0; ww < (t >> 6); ++ww) add += wsum[ww];
    v += add;                      // inclusive cum over buckets 0..t
    unsigned below = v - hv;
    if ((int)below < want && want <= (int)v) { ctr[0] = t; ctr[1] = (int)below; }
    __syncthreads();
    prefix |= ((unsigned)ctr[0]) << shift;
    want -= ctr[1];
  }
  const unsigned K32 = prefix;     // exact key value of rank-32 element

  // ---- gather selected indices (strict-less, then ties by smallest index) ----
  if (t < 2) ctr[2 + t] = 0;
  __syncthreads();
#pragma unroll
  for (int it = 0; it < 16; ++it) {
    unsigned k = key[it];
    int j = t + (it << 8);
    if (k < K32) {
      int p = atomicAdd(&ctr[2], 1);
      selidx[p] = j;
    } else if (k == K32) {
      int p = atomicAdd(&ctr[3], 1);
      if (p < 256) eqlist[p] = j;
    }
  }
  __syncthreads();
  int nsel = ctr[2];
  if (t == 0) {
    int m = 32 - nsel;
    int E = ctr[3] < 256 ? ctr[3] : 256;
    for (int sl = 0; sl < m; ++sl) {
      int bi = 0x7fffffff, be = 0;
      for (int e = 0; e < E; ++e) { int ix = eqlist[e]; if (ix < bi) { bi = ix; be = e; } }
      selidx[nsel + sl] = bi;
      eqlist[be] = 0x7fffffff;
    }
  }
  __syncthreads();

  // ---- features + mask for the 32 selected neighbors ----
  if (t < 32) {
    int j = selidx[t];
    float4 sj = ((const float4*)s)[j];
    float dx = __fsub_rn(si.x, sj.x);
    float dy = __fsub_rn(si.y, sj.y);
    xk[t][0] = dx; xk[t][1] = dy;
    xk[t][2] = __fsub_rn(si.z, sj.z);
    xk[t][3] = __fsub_rn(si.w, sj.w);
    xk[t][4] = (j == i) ? 1.0f : 0.0f;
    float nn = __fsqrt_rn(__fadd_rn(__fmul_rn(dx, dx), __fmul_rn(dy, dy)));
    maskv[t] = (nn < 1.0f) ? 1.0f : 0.0f;
  }
  __syncthreads();

  const int l  = t & 63, w = t >> 6;
  const int lm = l & 15, lh = l >> 4;

  // ---- layer 1 (5->64) computed directly into A-fragments (fp32 math, fp16 pack) ----
  // A fragment: lane l holds A[row][k], row=l&15 (+16*mt), k=4*(l>>4)+i (+16*ks)
  h4 af[2][4];
#pragma unroll
  for (int mt = 0; mt < 2; ++mt) {
    const float* xr = xk[16*mt + lm];
    float x0 = xr[0], x1 = xr[1], x2 = xr[2], x3 = xr[3], x4v = xr[4];
#pragma unroll
    for (int ks = 0; ks < 4; ++ks) {
#pragma unroll
      for (int i2 = 0; i2 < 4; ++i2) {
        int c = 16*ks + 4*lh + i2;
        const float* wr = &w1s[c*5];
        float h = b1s[c] + x0*wr[0] + x1*wr[1] + x2*wr[2] + x3*wr[3] + x4v*wr[4];
        af[mt][ks][i2] = (_Float16)fmaxf(h, 0.0f);
      }
    }
  }

  // ---- B fragments: coalesced 8B/lane loads from prepacked w2h ----
  h4 bf[2][4];
#pragma unroll
  for (int ntl = 0; ntl < 2; ++ntl) {
    int nt = 2*w + ntl;
#pragma unroll
    for (int ks = 0; ks < 4; ++ks)
      bf[ntl][ks] = w2h[(nt*4 + ks)*64 + l];
  }

  // ---- layer 2 (64->128 over 32 neighbors) via MFMA ----
  f4 acc[2][2] = {};
#pragma unroll
  for (int ks = 0; ks < 4; ++ks)
#pragma unroll
    for (int mt = 0; mt < 2; ++mt)
#pragma unroll
      for (int ntl = 0; ntl < 2; ++ntl)
        acc[mt][ntl] = __builtin_amdgcn_mfma_f32_16x16x16f16(af[mt][ks], bf[ntl][ks],
                                                             acc[mt][ntl], 0, 0, 0);

  // ---- epilogue: +b2, relu, mask, max over neighbors, write h ----
  // D fragment: lane l holds D[row][col], col=l&15, row=4*(l>>4)+j (+16*mt)
#pragma unroll
  for (int ntl = 0; ntl < 2; ++ntl) {
    int o = 16*(2*w + ntl) + lm;
    float bb = b2s[o];
    float best = 0.0f;                       // all masked products are >= 0
#pragma unroll
    for (int mt = 0; mt < 2; ++mt)
#pragma unroll
      for (int jj = 0; jj < 4; ++jj) {
        int rr = 16*mt + 4*lh + jj;
        float vv = fmaxf(acc[mt][ntl][jj] + bb, 0.0f) * maskv[rr];
        best = fmaxf(best, vv);
      }
    best = fmaxf(best, __shfl_xor(best, 16, 64));
    best = fmaxf(best, __shfl_xor(best, 32, 64));
    if (lh == 0) hws[i*128 + o] = best;
  }
}

// ---------------- kernel 2: head MLP, 16 rows per block ----------------
__global__ __launch_bounds__(256) void head_kernel(
    const float* __restrict__ s, const float* __restrict__ g,
    const float* __restrict__ fw1, const float* __restrict__ fb1,
    const float* __restrict__ fw2, const float* __restrict__ fb2,
    const float* __restrict__ fw3, const float* __restrict__ fb3,
    const float* __restrict__ fw4, const float* __restrict__ fb4,
    const float* __restrict__ hws, float* __restrict__ out) {
  const int t = threadIdx.x;
  const int base = blockIdx.x * 16;

  __shared__ float f0[16][136];   // h(128) + state(4), stride 136 (16B-aligned rows)
  __shared__ float f1[16][68];
  __shared__ float f2[16][132];
  __shared__ float f3[16][68];
  __shared__ float kk[16][4];

  for (int idx = t; idx < 16*128; idx += 256) {
    int r = idx >> 7, c = idx & 127;
    f0[r][c] = hws[(base + r)*128 + c];
  }
  if (t < 16) {
    int row = base + t;
    float4 sv = ((const float4*)s)[row];
    float2 gv = ((const float2*)g)[row];
    f0[t][128] = sv.x - gv.x;
    f0[t][129] = sv.y - gv.y;
    f0[t][130] = sv.z;
    f0[t][131] = sv.w;
  }
  __syncthreads();

  // L1: 132 -> 64
#pragma unroll
  for (int q = 0; q < 4; ++q) {
    int task = t + 256*q;
    int r = task >> 6, o = task & 63;
    const f4* wrow = (const f4*)(fw1 + o*132);
    const f4* frow = (const f4*)(&f0[r][0]);
    float acc = fb1[o];
#pragma unroll
    for (int qq = 0; qq < 33; ++qq) {
      f4 a = frow[qq], b = wrow[qq];
      acc += a[0]*b[0] + a[1]*b[1] + a[2]*b[2] + a[3]*b[3];
    }
    f1[r][o] = fmaxf(acc, 0.0f);
  }
  __syncthreads();
  // L2: 64 -> 128
#pragma unroll
  for (int q = 0; q < 8; ++q) {
    int task = t + 256*q;
    int r = task >> 7, o = task & 127;
    const f4* wrow = (const f4*)(fw2 + o*64);
    const f4* frow = (const f4*)(&f1[r][0]);
    float acc = fb2[o];
#pragma unroll
    for (int qq = 0; qq < 16; ++qq) {
      f4 a = frow[qq], b = wrow[qq];
      acc += a[0]*b[0] + a[1]*b[1] + a[2]*b[2] + a[3]*b[3];
    }
    f2[r][o] = fmaxf(acc, 0.0f);
  }
  __syncthreads();
  // L3: 128 -> 64
#pragma unroll
  for (int q = 0; q < 4; ++q) {
    int task = t + 256*q;
    int r = task >> 6, o = task & 63;
    const f4* wrow = (const f4*)(fw3 + o*128);
    const f4* frow = (const f4*)(&f2[r][0]);
    float acc = fb3[o];
#pragma unroll
    for (int qq = 0; qq < 32; ++qq) {
      f4 a = frow[qq], b = wrow[qq];
      acc += a[0]*b[0] + a[1]*b[1] + a[2]*b[2] + a[3]*b[3];
    }
    f3[r][o] = fmaxf(acc, 0.0f);
  }
  __syncthreads();
  // L4: 64 -> 4, sigmoid gains
  if (t < 64) {
    int r = t >> 2, oo = t & 3;
    const f4* wrow = (const f4*)(fw4 + oo*64);
    const f4* frow = (const f4*)(&f3[r][0]);
    float acc = fb4[oo];
#pragma unroll
    for (int qq = 0; qq < 16; ++qq) {
      f4 a = frow[qq], b = wrow[qq];
      acc += a[0]*b[0] + a[1]*b[1] + a[2]*b[2] + a[3]*b[3];
    }
    kk[r][oo] = 2.0f / (1.0f + expf(-acc)) + 0.2f;
  }
  __syncthreads();
  if (t < 16) {
    int row = base + t;
    float st0 = f0[t][128], st1 = f0[t][129], st2 = f0[t][130], st3 = f0[t][131];
    out[row*2]     = -(kk[t][0]*st0 + kk[t][1]*st2);
    out[row*2 + 1] = -(kk[t][2]*st1 + kk[t][3]*st3);
  }
}

extern "C" void kernel_launch(void* const* d_in, const int* in_sizes, int n_in,
                              void* d_out, int out_size, void* d_ws, size_t ws_size,
                              hipStream_t stream) {
  const float* s   = (const float*)d_in[0];
  const float* g   = (const float*)d_in[1];
  const float* w1  = (const float*)d_in[2];
  const float* b1  = (const float*)d_in[3];
  const float* w2  = (const float*)d_in[4];
  const float* b2  = (const float*)d_in[5];
  const float* fw1 = (const float*)d_in[6];
  const float* fb1 = (const float*)d_in[7];
  const float* fw2 = (const float*)d_in[8];
  const float* fb2 = (const float*)d_in[9];
  const float* fw3 = (const float*)d_in[10];
  const float* fb3 = (const float*)d_in[11];
  const float* fw4 = (const float*)d_in[12];
  const float* fb4 = (const float*)d_in[13];
  float* out = (float*)d_out;
  char* ws = (char*)d_ws;
  float2* sxy = (float2*)(ws + WS_SXY);
  h4* w2h = (h4*)(ws + WS_W2H);
  float* hws = (float*)(ws + WS_HWS);

  hipLaunchKernelGGL(prep_kernel, dim3(24), dim3(256), 0, stream, s, w2, sxy, w2h);
  hipLaunchKernelGGL(neigh_kernel, dim3(4096), dim3(256), 0, stream,
                     s, w1, b1, b2, sxy, w2h, hws);
  hipLaunchKernelGGL(head_kernel, dim3(256), dim3(256), 0, stream,
                     s, g, fw1, fb1, fw2, fb2, fw3, fb3, fw4, fb4, hws, out);
}

// Round 2
// 105.503 us; speedup vs baseline: 1.1929x; 1.1929x over previous
//
#include <hip/hip_runtime.h>

typedef _Float16 h4 __attribute__((ext_vector_type(4)));
typedef float f4 __attribute__((ext_vector_type(4)));

#define NPTS 4096

__device__ __forceinline__ void wbar() { __builtin_amdgcn_wave_barrier(); }

// ---------------- kernel 1: wave-per-row distances, exact top-32, edge MLP, masked max ----------------
__global__ __launch_bounds__(256) void neigh_kernel(
    const float* __restrict__ s, const float* __restrict__ w1,
    const float* __restrict__ b1, const float* __restrict__ w2,
    const float* __restrict__ b2, float* __restrict__ hws) {

  __shared__ float w1s[320];
  __shared__ float b1s[64];
  __shared__ float b2s[128];
  __shared__ h4 w2h[2048];               // 16 KB fragment-packed fp16 w2 (block-shared)
  __shared__ unsigned hist[4][4][256];   // [wave][copy][bin] 16 KB
  __shared__ unsigned wsel[4][2];        // per-wave scratch: {digit,below} / {append-cnt}
  __shared__ int selidx[4][32];
  __shared__ float xk[4][32][6];
  __shared__ float maskv[4][32];

  const int t = threadIdx.x;
  const int w = t >> 6;
  const int l = t & 63;

  // ---- block-shared weight staging (single barrier in whole kernel) ----
  for (int idx = t; idx < 320; idx += 256) w1s[idx] = w1[idx];
  if (t < 64)  b1s[t] = b1[t];
  if (t < 128) b2s[t] = b2[t];
#pragma unroll
  for (int q = 0; q < 8; ++q) {
    // B fragment for v_mfma_f32_16x16x16f16: lane fl holds B[k][col], col=fl&15, k=4*(fl>>4)+i
    int fi = t + 256*q;
    int fl = fi & 63, ks = (fi >> 6) & 3, nt = fi >> 8;
    int o  = 16*nt + (fl & 15);          // output channel (row of w2)
    int cb = 16*ks + 4*(fl >> 4);        // input channel (k dim)
    const float* wr = w2 + o*64 + cb;
    h4 v;
    v[0] = (_Float16)wr[0]; v[1] = (_Float16)wr[1];
    v[2] = (_Float16)wr[2]; v[3] = (_Float16)wr[3];
    w2h[fi] = v;
  }
  __syncthreads();

  const int i = blockIdx.x*4 + w;        // this wave's row
  const float4 si = ((const float4*)s)[i];

  // ---- distances: 64 keys/lane in registers (bitwise-IEEE to match np ref) ----
  const float2* s2 = (const float2*)s;
  unsigned key[64];
#pragma unroll
  for (int ii = 0; ii < 64; ++ii) {
    int j = l + (ii << 6);
    float2 p = s2[2*j];                  // (s[j][0], s[j][1])
    float dx = __fsub_rn(si.x, p.x);
    float dy = __fsub_rn(si.y, p.y);
    float a = __fadd_rn(__fmul_rn(dx, dx), 1e-6f);
    float b = __fadd_rn(__fmul_rn(dy, dy), 1e-6f);
    key[ii] = __float_as_uint(__fsqrt_rn(__fadd_rn(a, b)));
  }

  // ---- zero private histograms ----
  {
    uint4 z = make_uint4(0,0,0,0);
#pragma unroll
    for (int c = 0; c < 4; ++c) *(uint4*)&hist[w][c][4*l] = z;
  }
  wbar();

  // ---- exact radix select (4 x 8-bit, wave-synchronous, privatized hist) ----
  unsigned prefix = 0;
  int want = 32;

  // round 0 (all items valid)
#pragma unroll
  for (int ii = 0; ii < 64; ++ii)
    atomicAdd(&hist[w][l & 3][key[ii] >> 24], 1u);
  wbar();
#pragma unroll 1
  for (int r = 0; r < 4; ++r) {
    if (r > 0) {
      const int shift = 24 - 8*r;
      const unsigned himask = 0xFFFFFFFFu << (shift + 8);
#pragma unroll
      for (int ii = 0; ii < 64; ++ii) {
        unsigned k = key[ii];
        bool valid = (k & himask) == prefix;
        if (__ballot(valid) == 0ull) continue;
        if (valid) atomicAdd(&hist[w][l & 3][(k >> shift) & 255], 1u);
      }
      wbar();
    }
    // merge 4 copies + scan; lane l owns bins [4l,4l+4)
    uint4 h0 = *(uint4*)&hist[w][0][4*l];
    uint4 h1 = *(uint4*)&hist[w][1][4*l];
    uint4 h2 = *(uint4*)&hist[w][2][4*l];
    uint4 h3 = *(uint4*)&hist[w][3][4*l];
    unsigned c0 = h0.x+h1.x+h2.x+h3.x;
    unsigned c1 = h0.y+h1.y+h2.y+h3.y;
    unsigned c2 = h0.z+h1.z+h2.z+h3.z;
    unsigned c3 = h0.w+h1.w+h2.w+h3.w;
    unsigned s0 = c0, s1v = s0+c1, s2v = s1v+c2, s3v = s2v+c3;
    unsigned T = s3v, v = T;
#pragma unroll
    for (int off = 1; off < 64; off <<= 1) {
      unsigned n = __shfl_up(v, off, 64);
      if (l >= off) v += n;
    }
    unsigned excl = v - T;
    unsigned uw = (unsigned)want;
    if (excl       < uw && uw <= excl+s0)        { wsel[w][0] = 4*l+0; wsel[w][1] = excl; }
    if (excl+s0    < uw && uw <= excl+s1v)       { wsel[w][0] = 4*l+1; wsel[w][1] = excl+s0; }
    if (excl+s1v   < uw && uw <= excl+s2v)       { wsel[w][0] = 4*l+2; wsel[w][1] = excl+s1v; }
    if (excl+s2v   < uw && uw <= excl+s3v)       { wsel[w][0] = 4*l+3; wsel[w][1] = excl+s2v; }
    wbar();
    unsigned d = wsel[w][0], below = wsel[w][1];
    prefix |= d << (24 - 8*r);
    want -= (int)below;
    if (r < 3) {   // re-zero for next round
      uint4 z = make_uint4(0,0,0,0);
      wbar();
#pragma unroll
      for (int c = 0; c < 4; ++c) *(uint4*)&hist[w][c][4*l] = z;
      wbar();
    }
  }
  const unsigned K32 = prefix;           // exact key of rank-32 smallest

  // ---- gather: strict-less (any order), then ties by smallest index ----
  if (l == 0) wsel[w][0] = 0;
  wbar();
#pragma unroll
  for (int ii = 0; ii < 64; ++ii) {
    unsigned k = key[ii];
    if (__ballot(k <= K32) == 0ull) continue;
    if (k < K32) {
      unsigned pos = atomicAdd(&wsel[w][0], 1u);
      selidx[w][pos] = l + (ii << 6);
    }
  }
  wbar();
  int nsel = (int)wsel[w][0];
  int m = 32 - nsel;                     // >= 1 by rank definition
  int last = -1;
#pragma unroll 1
  for (int slot = 0; slot < m; ++slot) {
    int mn = 0x7FFFFFFF;
#pragma unroll
    for (int ii = 0; ii < 64; ++ii) {
      int j = l + (ii << 6);
      if (key[ii] == K32 && j > last && j < mn) mn = j;
    }
#pragma unroll
    for (int off = 1; off < 64; off <<= 1) mn = min(mn, __shfl_xor(mn, off, 64));
    if (l == 0) selidx[w][nsel + slot] = mn;
    last = mn;
  }
  wbar();

  // ---- features + mask for the 32 selected neighbors ----
  if (l < 32) {
    int j = selidx[w][l];
    float4 sj = ((const float4*)s)[j];
    float dx = __fsub_rn(si.x, sj.x);
    float dy = __fsub_rn(si.y, sj.y);
    xk[w][l][0] = dx; xk[w][l][1] = dy;
    xk[w][l][2] = __fsub_rn(si.z, sj.z);
    xk[w][l][3] = __fsub_rn(si.w, sj.w);
    xk[w][l][4] = (j == i) ? 1.0f : 0.0f;
    float nn = __fsqrt_rn(__fadd_rn(__fmul_rn(dx, dx), __fmul_rn(dy, dy)));
    maskv[w][l] = (nn < 1.0f) ? 1.0f : 0.0f;
  }
  wbar();

  // ---- layer 1 (5->64) into A-fragments; layer 2 (64->128) via MFMA ----
  const int lm = l & 15, lh = l >> 4;
  h4 af[2][4];
#pragma unroll
  for (int mt = 0; mt < 2; ++mt) {
    const float* xr = xk[w][16*mt + lm];
    float x0 = xr[0], x1 = xr[1], x2 = xr[2], x3 = xr[3], x4v = xr[4];
#pragma unroll
    for (int ks = 0; ks < 4; ++ks)
#pragma unroll
      for (int i2 = 0; i2 < 4; ++i2) {
        int c = 16*ks + 4*lh + i2;
        const float* wr = &w1s[c*5];
        float h = b1s[c] + x0*wr[0] + x1*wr[1] + x2*wr[2] + x3*wr[3] + x4v*wr[4];
        af[mt][ks][i2] = (_Float16)fmaxf(h, 0.0f);
      }
  }

#pragma unroll
  for (int half = 0; half < 2; ++half) {
    h4 bf[4][4];
#pragma unroll
    for (int ntl = 0; ntl < 4; ++ntl) {
      int nt = 4*half + ntl;
#pragma unroll
      for (int ks = 0; ks < 4; ++ks)
        bf[ntl][ks] = w2h[(nt*4 + ks)*64 + l];
    }
    f4 acc[2][4] = {};
#pragma unroll
    for (int ks = 0; ks < 4; ++ks)
#pragma unroll
      for (int mt = 0; mt < 2; ++mt)
#pragma unroll
        for (int ntl = 0; ntl < 4; ++ntl)
          acc[mt][ntl] = __builtin_amdgcn_mfma_f32_16x16x16f16(af[mt][ks], bf[ntl][ks],
                                                               acc[mt][ntl], 0, 0, 0);
    // epilogue: +b2, relu, mask, max over 32 neighbors, write h
#pragma unroll
    for (int ntl = 0; ntl < 4; ++ntl) {
      int o = 16*(4*half + ntl) + lm;
      float bb = b2s[o];
      float best = 0.0f;                 // all masked products >= 0
#pragma unroll
      for (int mt = 0; mt < 2; ++mt)
#pragma unroll
        for (int jj = 0; jj < 4; ++jj) {
          int rr = 16*mt + 4*lh + jj;
          float vv = fmaxf(acc[mt][ntl][jj] + bb, 0.0f) * maskv[w][rr];
          best = fmaxf(best, vv);
        }
      best = fmaxf(best, __shfl_xor(best, 16, 64));
      best = fmaxf(best, __shfl_xor(best, 32, 64));
      if (lh == 0) hws[i*128 + o] = best;
    }
  }
}

// ---------------- kernel 2: head MLP, 16 rows per block ----------------
__global__ __launch_bounds__(256) void head_kernel(
    const float* __restrict__ s, const float* __restrict__ g,
    const float* __restrict__ fw1, const float* __restrict__ fb1,
    const float* __restrict__ fw2, const float* __restrict__ fb2,
    const float* __restrict__ fw3, const float* __restrict__ fb3,
    const float* __restrict__ fw4, const float* __restrict__ fb4,
    const float* __restrict__ hws, float* __restrict__ out) {
  const int t = threadIdx.x;
  const int base = blockIdx.x * 16;

  __shared__ float f0[16][136];   // h(128) + state(4)
  __shared__ float f1[16][68];
  __shared__ float f2[16][132];
  __shared__ float f3[16][68];
  __shared__ float kk[16][4];

  for (int idx = t; idx < 16*128; idx += 256) {
    int r = idx >> 7, c = idx & 127;
    f0[r][c] = hws[(base + r)*128 + c];
  }
  if (t < 16) {
    int row = base + t;
    float4 sv = ((const float4*)s)[row];
    float2 gv = ((const float2*)g)[row];
    f0[t][128] = sv.x - gv.x;
    f0[t][129] = sv.y - gv.y;
    f0[t][130] = sv.z;
    f0[t][131] = sv.w;
  }
  __syncthreads();

  // L1: 132 -> 64
#pragma unroll
  for (int q = 0; q < 4; ++q) {
    int task = t + 256*q;
    int r = task >> 6, o = task & 63;
    const f4* wrow = (const f4*)(fw1 + o*132);
    const f4* frow = (const f4*)(&f0[r][0]);
    float acc = fb1[o];
#pragma unroll
    for (int qq = 0; qq < 33; ++qq) {
      f4 a = frow[qq], b = wrow[qq];
      acc += a[0]*b[0] + a[1]*b[1] + a[2]*b[2] + a[3]*b[3];
    }
    f1[r][o] = fmaxf(acc, 0.0f);
  }
  __syncthreads();
  // L2: 64 -> 128
#pragma unroll
  for (int q = 0; q < 8; ++q) {
    int task = t + 256*q;
    int r = task >> 7, o = task & 127;
    const f4* wrow = (const f4*)(fw2 + o*64);
    const f4* frow = (const f4*)(&f1[r][0]);
    float acc = fb2[o];
#pragma unroll
    for (int qq = 0; qq < 16; ++qq) {
      f4 a = frow[qq], b = wrow[qq];
      acc += a[0]*b[0] + a[1]*b[1] + a[2]*b[2] + a[3]*b[3];
    }
    f2[r][o] = fmaxf(acc, 0.0f);
  }
  __syncthreads();
  // L3: 128 -> 64
#pragma unroll
  for (int q = 0; q < 4; ++q) {
    int task = t + 256*q;
    int r = task >> 6, o = task & 63;
    const f4* wrow = (const f4*)(fw3 + o*128);
    const f4* frow = (const f4*)(&f2[r][0]);
    float acc = fb3[o];
#pragma unroll
    for (int qq = 0; qq < 32; ++qq) {
      f4 a = frow[qq], b = wrow[qq];
      acc += a[0]*b[0] + a[1]*b[1] + a[2]*b[2] + a[3]*b[3];
    }
    f3[r][o] = fmaxf(acc, 0.0f);
  }
  __syncthreads();
  // L4: 64 -> 4, sigmoid gains
  if (t < 64) {
    int r = t >> 2, oo = t & 3;
    const f4* wrow = (const f4*)(fw4 + oo*64);
    const f4* frow = (const f4*)(&f3[r][0]);
    float acc = fb4[oo];
#pragma unroll
    for (int qq = 0; qq < 16; ++qq) {
      f4 a = frow[qq], b = wrow[qq];
      acc += a[0]*b[0] + a[1]*b[1] + a[2]*b[2] + a[3]*b[3];
    }
    kk[r][oo] = 2.0f / (1.0f + expf(-acc)) + 0.2f;
  }
  __syncthreads();
  if (t < 16) {
    int row = base + t;
    float st0 = f0[t][128], st1 = f0[t][129], st2 = f0[t][130], st3 = f0[t][131];
    out[row*2]     = -(kk[t][0]*st0 + kk[t][1]*st2);
    out[row*2 + 1] = -(kk[t][2]*st1 + kk[t][3]*st3);
  }
}

extern "C" void kernel_launch(void* const* d_in, const int* in_sizes, int n_in,
                              void* d_out, int out_size, void* d_ws, size_t ws_size,
                              hipStream_t stream) {
  const float* s   = (const float*)d_in[0];
  const float* g   = (const float*)d_in[1];
  const float* w1  = (const float*)d_in[2];
  const float* b1  = (const float*)d_in[3];
  const float* w2  = (const float*)d_in[4];
  const float* b2  = (const float*)d_in[5];
  const float* fw1 = (const float*)d_in[6];
  const float* fb1 = (const float*)d_in[7];
  const float* fw2 = (const float*)d_in[8];
  const float* fb2 = (const float*)d_in[9];
  const float* fw3 = (const float*)d_in[10];
  const float* fb3 = (const float*)d_in[11];
  const float* fw4 = (const float*)d_in[12];
  const float* fb4 = (const float*)d_in[13];
  float* out = (float*)d_out;
  float* hws = (float*)d_ws;             // 4096*128 floats

  hipLaunchKernelGGL(neigh_kernel, dim3(1024), dim3(256), 0, stream,
                     s, w1, b1, w2, b2, hws);
  hipLaunchKernelGGL(head_kernel, dim3(256), dim3(256), 0, stream,
                     s, g, fw1, fb1, fw2, fb2, fw3, fb3, fw4, fb4, hws, out);
}

// Round 3
// 42.144 us; speedup vs baseline: 2.9864x; 2.5034x over previous
//
#include <hip/hip_runtime.h>

typedef _Float16 h4 __attribute__((ext_vector_type(4)));
typedef float f4 __attribute__((ext_vector_type(4)));
typedef _Float16 half_t;

#define WS_W2H   0
#define WS_WF1   16384
#define WS_WF2   34816
#define WS_WF3   51200
#define WS_HWS   69632

__device__ __forceinline__ void wbar() { __builtin_amdgcn_wave_barrier(); }

// ---------------- prep: pack all MFMA B-operands to fragment-ordered fp16 ----------------
__global__ __launch_bounds__(256) void prep_kernel(
    const float* __restrict__ w2, const float* __restrict__ fw1,
    const float* __restrict__ fw2, const float* __restrict__ fw3,
    h4* __restrict__ w2h, h4* __restrict__ wf1h,
    h4* __restrict__ wf2h, h4* __restrict__ wf3h) {
  int tid = blockIdx.x*256 + threadIdx.x;
  // B fragment for v_mfma_f32_16x16x16f16: lane fl holds B[k][col], col=fl&15, k=4*(fl>>4)+i
  if (tid < 2048) {                       // edge w2: K=64, N=128
    int fl = tid & 63, ks = (tid>>6)&3, nt = tid>>8;
    int o = 16*nt + (fl&15), cb = 16*ks + 4*(fl>>4);
    const float* wr = w2 + o*64 + cb;
    h4 v; v[0]=(half_t)wr[0]; v[1]=(half_t)wr[1]; v[2]=(half_t)wr[2]; v[3]=(half_t)wr[3];
    w2h[tid] = v;
  } else if (tid < 4352) {                // fw1: K=144(pad from 132), N=64 -> ktiles 9
    int idx = tid - 2048;
    int fl = idx & 63, rem = idx >> 6;    // 0..35
    int kt = rem % 9, nt = rem / 9;
    int n = 16*nt + (fl&15), k0 = 16*kt + 4*(fl>>4);
    h4 v;
#pragma unroll
    for (int q=0;q<4;++q) { int k = k0+q; v[q] = (k<132)?(half_t)fw1[n*132+k]:(half_t)0.f; }
    wf1h[idx] = v;
  } else if (tid < 6400) {                // fw2: K=64, N=128
    int idx = tid - 4352;
    int fl = idx & 63, rem = idx >> 6;
    int kt = rem & 3, nt = rem >> 2;
    int n = 16*nt + (fl&15), k0 = 16*kt + 4*(fl>>4);
    h4 v;
#pragma unroll
    for (int q=0;q<4;++q) v[q] = (half_t)fw2[n*64 + k0 + q];
    wf2h[idx] = v;
  } else if (tid < 8448) {                // fw3: K=128, N=64
    int idx = tid - 6400;
    int fl = idx & 63, rem = idx >> 6;
    int kt = rem & 7, nt = rem >> 3;
    int n = 16*nt + (fl&15), k0 = 16*kt + 4*(fl>>4);
    h4 v;
#pragma unroll
    for (int q=0;q<4;++q) v[q] = (half_t)fw3[n*128 + k0 + q];
    wf3h[idx] = v;
  }
}

// ---------------- kernel 1: wave-per-row, 1-round radix top-32, edge MLP, masked max ----------------
__global__ __launch_bounds__(64, 4) void neigh_kernel(
    const float* __restrict__ s, const float* __restrict__ w1,
    const float* __restrict__ b1, const float* __restrict__ b2,
    const h4* __restrict__ w2h, half_t* __restrict__ hws) {
  __shared__ unsigned hist[2][512];
  __shared__ unsigned cand[256];
  __shared__ int selq[32];
  __shared__ unsigned wst[4];   // 0:B 1:below 2:nsel 3:candcnt
  __shared__ float w1s[320], b1s[64], b2s[128];
  __shared__ float xk[32][6];
  __shared__ float maskv[32];

  const int l = threadIdx.x;
  const int i = blockIdx.x;

#pragma unroll
  for (int q=0;q<5;++q) w1s[l+64*q] = w1[l+64*q];
  b1s[l] = b1[l];
  b2s[l] = b2[l]; b2s[l+64] = b2[l+64];
  {
    uint4 z = make_uint4(0,0,0,0);
    *(uint4*)&hist[0][4*l] = z; *(uint4*)&hist[0][4*l+256] = z;
    *(uint4*)&hist[1][4*l] = z; *(uint4*)&hist[1][4*l+256] = z;
  }
  if (l < 4) wst[l] = 0;
  wbar();

  const float4 si = ((const float4*)s)[i];
  const float2* s2 = (const float2*)s;

  // ---- distances -> compressed 27-bit monotone keys (bitwise-IEEE) + 9-bit histogram ----
  unsigned key[64];
#pragma unroll
  for (int ii=0; ii<64; ++ii) {
    int j = l + (ii<<6);
    float2 p = s2[2*j];
    float dx = __fsub_rn(si.x, p.x);
    float dy = __fsub_rn(si.y, p.y);
    float a = __fadd_rn(__fmul_rn(dx,dx), 1e-6f);
    float b = __fadd_rn(__fmul_rn(dy,dy), 1e-6f);
    unsigned k = __float_as_uint(__fsqrt_rn(__fadd_rn(a,b)));
    unsigned ck = (unsigned)min(max((int)k - 0x3A000000, 0), 0x07FFFFFF);
    key[ii] = ck;
    atomicAdd(&hist[l&1][ck>>18], 1u);
  }
  wbar();

  // ---- scan 512 bins (lane owns 8), find bucket B where cum crosses 32 ----
  {
    uint4 hA0 = *(uint4*)&hist[0][8*l], hA1 = *(uint4*)&hist[0][8*l+4];
    uint4 hB0 = *(uint4*)&hist[1][8*l], hB1 = *(uint4*)&hist[1][8*l+4];
    unsigned c[8] = {hA0.x+hB0.x, hA0.y+hB0.y, hA0.z+hB0.z, hA0.w+hB0.w,
                     hA1.x+hB1.x, hA1.y+hB1.y, hA1.z+hB1.z, hA1.w+hB1.w};
    unsigned p[8], run = 0;
#pragma unroll
    for (int q=0;q<8;++q) { run += c[q]; p[q] = run; }
    unsigned tot = run, v = tot;
#pragma unroll
    for (int off=1; off<64; off<<=1) {
      unsigned n = __shfl_up(v, off, 64);
      if (l >= off) v += n;
    }
    unsigned excl = v - tot;
    unsigned prev = excl;
#pragma unroll
    for (int q=0;q<8;++q) {
      unsigned cur = excl + p[q];
      if (prev < 32u && cur >= 32u) { wst[0] = 8*l+q; wst[1] = prev; }
      prev = cur;
    }
  }
  wbar();
  const unsigned B = wst[0];
  const int below = (int)wst[1];

  // ---- compact: digit<B -> selected (unordered); digit==B -> boundary candidates ----
#pragma unroll
  for (int ii=0; ii<64; ++ii) {
    unsigned ck = key[ii];
    unsigned d = ck >> 18;
    int j = l + (ii<<6);
    if (d < B) {
      unsigned pos = atomicAdd(&wst[2], 1u);
      selq[pos] = j;
    } else if (d == B) {
      unsigned pos = atomicAdd(&wst[3], 1u);
      if (pos < 256u) cand[pos] = ((ck & 0x3FFFFu) << 12) | (unsigned)j;
    }
  }
  wbar();

  // ---- extract (32-below) smallest by (key, idx): exact reference tie-break ----
  {
    int cnt = (int)wst[3];
    unsigned c0 = (l       < cnt) ? cand[l]     : 0xFFFFFFFFu;
    unsigned c1 = (l + 64  < cnt) ? cand[l+64]  : 0xFFFFFFFFu;
    unsigned c2 = (l + 128 < cnt) ? cand[l+128] : 0xFFFFFFFFu;
    unsigned c3 = (l + 192 < cnt) ? cand[l+192] : 0xFFFFFFFFu;
    int want = 32 - below;
#pragma unroll 1
    for (int it=0; it<want; ++it) {
      unsigned mn = min(min(c0,c1), min(c2,c3));
#pragma unroll
      for (int off=1; off<64; off<<=1) mn = min(mn, __shfl_xor(mn, off, 64));
      c0 = (c0==mn)?0xFFFFFFFFu:c0;
      c1 = (c1==mn)?0xFFFFFFFFu:c1;
      c2 = (c2==mn)?0xFFFFFFFFu:c2;
      c3 = (c3==mn)?0xFFFFFFFFu:c3;
      if (l == 0) selq[below + it] = (int)(mn & 0xFFFu);
    }
  }
  wbar();

  // ---- features + mask ----
  if (l < 32) {
    int j = selq[l];
    float4 sj = ((const float4*)s)[j];
    float dx = __fsub_rn(si.x, sj.x);
    float dy = __fsub_rn(si.y, sj.y);
    xk[l][0] = dx; xk[l][1] = dy;
    xk[l][2] = __fsub_rn(si.z, sj.z);
    xk[l][3] = __fsub_rn(si.w, sj.w);
    xk[l][4] = (j == i) ? 1.0f : 0.0f;
    float nn = __fsqrt_rn(__fadd_rn(__fmul_rn(dx,dx), __fmul_rn(dy,dy)));
    maskv[l] = (nn < 1.0f) ? 1.0f : 0.0f;
  }
  wbar();

  // ---- edge layer 1 (5->64) into A-frags; layer 2 (64->128) via MFMA ----
  const int lm = l & 15, lh = l >> 4;
  h4 af[2][4];
#pragma unroll
  for (int mt=0; mt<2; ++mt) {
    const float* xr = xk[16*mt + lm];
    float x0=xr[0], x1=xr[1], x2=xr[2], x3=xr[3], x4v=xr[4];
#pragma unroll
    for (int ks=0; ks<4; ++ks)
#pragma unroll
      for (int i2=0; i2<4; ++i2) {
        int c = 16*ks + 4*lh + i2;
        const float* wr = &w1s[c*5];
        float h = b1s[c] + x0*wr[0] + x1*wr[1] + x2*wr[2] + x3*wr[3] + x4v*wr[4];
        af[mt][ks][i2] = (half_t)fmaxf(h, 0.0f);
      }
  }

#pragma unroll
  for (int hf=0; hf<2; ++hf) {
    h4 bf[4][4];
#pragma unroll
    for (int ntl=0; ntl<4; ++ntl) {
      int nt = 4*hf + ntl;
#pragma unroll
      for (int ks=0; ks<4; ++ks) bf[ntl][ks] = w2h[(nt*4+ks)*64 + l];
    }
    f4 acc[2][4] = {};
#pragma unroll
    for (int ks=0; ks<4; ++ks)
#pragma unroll
      for (int mt=0; mt<2; ++mt)
#pragma unroll
        for (int ntl=0; ntl<4; ++ntl)
          acc[mt][ntl] = __builtin_amdgcn_mfma_f32_16x16x16f16(af[mt][ks], bf[ntl][ks],
                                                               acc[mt][ntl], 0, 0, 0);
#pragma unroll
    for (int ntl=0; ntl<4; ++ntl) {
      int o = 16*(4*hf + ntl) + lm;
      float bb = b2s[o];
      float best = 0.0f;
#pragma unroll
      for (int mt=0; mt<2; ++mt)
#pragma unroll
        for (int jj=0; jj<4; ++jj) {
          int rr = 16*mt + 4*lh + jj;
          float vv = fmaxf(acc[mt][ntl][jj] + bb, 0.0f) * maskv[rr];
          best = fmaxf(best, vv);
        }
      best = fmaxf(best, __shfl_xor(best, 16, 64));
      best = fmaxf(best, __shfl_xor(best, 32, 64));
      if (lh == 0) hws[i*128 + o] = (half_t)best;
    }
  }
}

// ---------------- kernel 2: head MLP via MFMA, 16 rows/block ----------------
__global__ __launch_bounds__(256) void head_kernel(
    const float* __restrict__ s, const float* __restrict__ g,
    const h4* __restrict__ wf1h, const float* __restrict__ fb1,
    const h4* __restrict__ wf2h, const float* __restrict__ fb2,
    const h4* __restrict__ wf3h, const float* __restrict__ fb3,
    const float* __restrict__ fw4, const float* __restrict__ fb4,
    const half_t* __restrict__ hws, float* __restrict__ out) {
  const int t = threadIdx.x, base = blockIdx.x*16;
  const int w = t>>6, l = t&63, lm = l&15, lh = l>>4;
  __shared__ half_t a0[16][152];   // stride 152h=304B: 16B-aligned rows, 2-way max on frag reads
  __shared__ half_t a1[16][68];
  __shared__ half_t a2[16][132];
  __shared__ float  a3[16][68];
  __shared__ float  kv[16][4];

  // stage act0 = [h(128 fp16) | state(4) | zeros(pad)]
  if (t < 128) {
    int r = t>>3, c0 = (t&7)*16;
    const uint4* src = (const uint4*)(hws + (base+r)*128 + c0);
    uint4 u0 = src[0], u1 = src[1];
    *(uint4*)&a0[r][c0] = u0;
    *(uint4*)&a0[r][c0+8] = u1;
  }
  if (t < 16) {
    float4 sv = ((const float4*)s)[base+t];
    float2 gv = ((const float2*)g)[base+t];
    a0[t][128] = (half_t)(sv.x - gv.x);
    a0[t][129] = (half_t)(sv.y - gv.y);
    a0[t][130] = (half_t)sv.z;
    a0[t][131] = (half_t)sv.w;
    *(uint2*)&a0[t][132] = make_uint2(0,0);
    *(uint4*)&a0[t][136] = make_uint4(0,0,0,0);
    *(uint4*)&a0[t][144] = make_uint4(0,0,0,0);
  }
  __syncthreads();

  // L1: [16x144]x[144x64]; wave w -> cols 16w..16w+15
  {
    h4 bf[9];
#pragma unroll
    for (int kt=0; kt<9; ++kt) bf[kt] = wf1h[(w*9 + kt)*64 + l];
    f4 acc = {};
#pragma unroll
    for (int kt=0; kt<9; ++kt) {
      h4 a = *(const h4*)&a0[lm][16*kt + 4*lh];
      acc = __builtin_amdgcn_mfma_f32_16x16x16f16(a, bf[kt], acc, 0,0,0);
    }
    int col = 16*w + lm;
    float bb = fb1[col];
#pragma unroll
    for (int jj=0;jj<4;++jj)
      a1[4*lh+jj][col] = (half_t)fmaxf(acc[jj] + bb, 0.0f);
  }
  __syncthreads();
  // L2: [16x64]x[64x128]; wave w -> ntiles 2w,2w+1
  {
    h4 bf[2][4];
#pragma unroll
    for (int u=0;u<2;++u) { int nt = 2*w+u;
#pragma unroll
      for (int kt=0;kt<4;++kt) bf[u][kt] = wf2h[(nt*4+kt)*64 + l]; }
    f4 acc[2] = {};
#pragma unroll
    for (int kt=0;kt<4;++kt) {
      h4 a = *(const h4*)&a1[lm][16*kt + 4*lh];
#pragma unroll
      for (int u=0;u<2;++u)
        acc[u] = __builtin_amdgcn_mfma_f32_16x16x16f16(a, bf[u][kt], acc[u], 0,0,0);
    }
#pragma unroll
    for (int u=0;u<2;++u) {
      int col = 16*(2*w+u) + lm;
      float bb = fb2[col];
#pragma unroll
      for (int jj=0;jj<4;++jj)
        a2[4*lh+jj][col] = (half_t)fmaxf(acc[u][jj] + bb, 0.0f);
    }
  }
  __syncthreads();
  // L3: [16x128]x[128x64] -> fp32 act
  {
    h4 bf[8];
#pragma unroll
    for (int kt=0;kt<8;++kt) bf[kt] = wf3h[(w*8+kt)*64 + l];
    f4 acc = {};
#pragma unroll
    for (int kt=0;kt<8;++kt) {
      h4 a = *(const h4*)&a2[lm][16*kt + 4*lh];
      acc = __builtin_amdgcn_mfma_f32_16x16x16f16(a, bf[kt], acc, 0,0,0);
    }
    int col = 16*w + lm;
    float bb = fb3[col];
#pragma unroll
    for (int jj=0;jj<4;++jj)
      a3[4*lh+jj][col] = fmaxf(acc[jj] + bb, 0.0f);
  }
  __syncthreads();
  // L4: 64->4 fp32 + sigmoid gains
  if (t < 64) {
    int r = t>>2, oo = t&3;
    const f4* wrow = (const f4*)(fw4 + oo*64);
    const f4* arow = (const f4*)&a3[r][0];
    float acc = fb4[oo];
#pragma unroll
    for (int q=0;q<16;++q) {
      f4 a = arow[q], b = wrow[q];
      acc += a[0]*b[0] + a[1]*b[1] + a[2]*b[2] + a[3]*b[3];
    }
    kv[r][oo] = 2.0f / (1.0f + expf(-acc)) + 0.2f;
  }
  __syncthreads();
  if (t < 16) {
    int row = base + t;
    float4 sv = ((const float4*)s)[row];
    float2 gv = ((const float2*)g)[row];
    float st0 = sv.x - gv.x, st1 = sv.y - gv.y;
    out[row*2]   = -(kv[t][0]*st0 + kv[t][1]*sv.z);
    out[row*2+1] = -(kv[t][2]*st1 + kv[t][3]*sv.w);
  }
}

extern "C" void kernel_launch(void* const* d_in, const int* in_sizes, int n_in,
                              void* d_out, int out_size, void* d_ws, size_t ws_size,
                              hipStream_t stream) {
  const float* s   = (const float*)d_in[0];
  const float* g   = (const float*)d_in[1];
  const float* w1  = (const float*)d_in[2];
  const float* b1  = (const float*)d_in[3];
  const float* w2  = (const float*)d_in[4];
  const float* b2  = (const float*)d_in[5];
  const float* fw1 = (const float*)d_in[6];
  const float* fb1 = (const float*)d_in[7];
  const float* fw2 = (const float*)d_in[8];
  const float* fb2 = (const float*)d_in[9];
  const float* fw3 = (const float*)d_in[10];
  const float* fb3 = (const float*)d_in[11];
  const float* fw4 = (const float*)d_in[12];
  const float* fb4 = (const float*)d_in[13];
  float* out = (float*)d_out;
  char* ws = (char*)d_ws;
  h4* w2h  = (h4*)(ws + WS_W2H);
  h4* wf1h = (h4*)(ws + WS_WF1);
  h4* wf2h = (h4*)(ws + WS_WF2);
  h4* wf3h = (h4*)(ws + WS_WF3);
  half_t* hws = (half_t*)(ws + WS_HWS);

  hipLaunchKernelGGL(prep_kernel, dim3(33), dim3(256), 0, stream,
                     w2, fw1, fw2, fw3, w2h, wf1h, wf2h, wf3h);
  hipLaunchKernelGGL(neigh_kernel, dim3(4096), dim3(64), 0, stream,
                     s, w1, b1, b2, w2h, hws);
  hipLaunchKernelGGL(head_kernel, dim3(256), dim3(256), 0, stream,
                     s, g, wf1h, fb1, wf2h, fb2, wf3h, fb3, fw4, fb4, hws, out);
}